// Round 5
// baseline (202.423 us; speedup 1.0000x reference)
//
#include <hip/hip_runtime.h>

#define BB 256
#define TT 1024
#define VV 64
#define LL 64
#define NEGF  (-1e30f)
#define LOG2E 1.4426950408889634f
#define LN2   0.6931471805599453f

__device__ __forceinline__ int   f2i(float x) { return __float_as_int(x); }
__device__ __forceinline__ float i2f(int x)   { return __int_as_float(x); }

// base-2 logaddexp (hardware-native: v_exp_f32/v_log_f32 are 2^x / log2)
__device__ __forceinline__ float lae2_2(float a, float b) {
  float m = fmaxf(a, b);
  float d = fminf(a, b) - m;          // 0 if both equal (incl. both NEGF)
  return m + __builtin_amdgcn_logf(1.0f + __builtin_amdgcn_exp2f(d));
}

// ---------- Phase 1: per-block partial sums of log-sum-exp over valid t ----------
// grid: B*16 blocks of 256 threads; block bid covers 64 t-rows of b = bid>>4.
// Writes partials[bid] (pure store, no init needed). Block 0 also zeroes out[0].
extern "C" __global__ void __launch_bounds__(256)
ctc_lse(const float* __restrict__ logits, const int* __restrict__ mask,
        float* __restrict__ partials, float* __restrict__ out) {
  const int bid = blockIdx.x;
  const int b   = bid >> 4;
  const int tb  = (bid & 15) << 6;
  const int tid = threadIdx.x;
  const int lane = tid & 63;
  const int w    = tid >> 6;

  if (bid == 0 && tid == 0) out[0] = 0.0f;   // d_out is re-poisoned before each call

  const float* lg = logits + (size_t)b * TT * VV;
  const int colv = (lane & 15) << 2;

  float acc = 0.0f;
#pragma unroll
  for (int p = 0; p < 4; ++p) {
    const int rowT = tb + (w << 4) + (p << 2) + (lane >> 4);
    const float4 v = *(const float4*)(lg + (size_t)rowT * VV + colv);
    float s = __expf(v.x) + __expf(v.y) + __expf(v.z) + __expf(v.w);
    s += __shfl_xor(s, 1);
    s += __shfl_xor(s, 2);
    s += __shfl_xor(s, 4);
    s += __shfl_xor(s, 8);             // 16-lane group sum -> row LSE argument
    if ((lane & 15) == 0) {
      const int mv = mask[b * TT + rowT];   // prefix-true: mv!=0 <=> t < len
      acc += mv ? __logf(s) : 0.0f;
    }
  }
  acc = ((lane & 15) == 0) ? acc : 0.0f;
  acc += __shfl_xor(acc, 16);
  acc += __shfl_xor(acc, 32);

  __shared__ float wsum[4];
  if (lane == 0) wsum[w] = acc;
  __syncthreads();
  if (tid == 0) partials[bid] = wsum[0] + wsum[1] + wsum[2] + wsum[3];
}

// ---------- Phase 2: sequential alpha DP on RAW logits, base-2 log space ----------
// One wave per b. Lane l holds alpha[2l] (a0), alpha[2l+1] (a1); lane63 also
// alpha[128] (a2). Ring = 32 NAMED scalars, macro-unrolled 16-step body.
// __launch_bounds__(64, 1): min-1-wave/EU lifts the VGPR budget to ~512 so the
// scheduler keeps the ring resident instead of sinking loads to their uses
// (observed: default bounds -> VGPR=28, every step eats a ~200cyc L2 latency).
extern "C" __global__ void __launch_bounds__(64, 1)
ctc_dp(const int* __restrict__ labels, const float* __restrict__ logits,
       const int* __restrict__ mask, const float* __restrict__ partials,
       float* __restrict__ out) {
  const int b = blockIdx.x;
  const int lane = threadIdx.x;

  const int lab = labels[b * LL + lane];                 // label for state 2*lane+1
  const int lab_len = (int)__popcll(__ballot(lab != 0));

  // sum of per-block LSE partials for this b (16 slots)
  float psum = (lane < 16) ? partials[(b << 4) + lane] : 0.0f;
  psum += __shfl_xor(psum, 1);
  psum += __shfl_xor(psum, 2);
  psum += __shfl_xor(psum, 4);
  psum += __shfl_xor(psum, 8);
  const float sumLse = i2f(__builtin_amdgcn_readfirstlane(f2i(psum)));

  // logits_len = popcount of prefix-true mask row
  int lsum = 0;
  const int* mrow = mask + b * TT;
#pragma unroll
  for (int k = 0; k < TT / 64; ++k) lsum += mrow[lane + (k << 6)];
#pragma unroll
  for (int off = 32; off; off >>= 1) lsum += __shfl_xor(lsum, off);
  int len = __builtin_amdgcn_readfirstlane(lsum);
  len = len < 1 ? 1 : (len > TT ? TT : len);

  // allow_skip for odd state: lab != 0 && lab != prev lab
  const int plab = __builtin_amdgcn_update_dpp(0, lab, 0x138, 0xF, 0xF, false); // wave_shr:1
  const bool skip_ok = (lab != 0) && (lab != plab);

  const float* lg   = logits + (size_t)b * TT * VV;
  const float* glab = lg + (lab & 63);                   // per-lane gather base

  // prefetch ring: 32 named scalars, depth 16
  float xg0, xg1, xg2, xg3, xg4, xg5, xg6, xg7, xg8, xg9, xg10, xg11, xg12, xg13, xg14, xg15;
  float xb0, xb1, xb2, xb3, xb4, xb5, xb6, xb7, xb8, xb9, xb10, xb11, xb12, xb13, xb14, xb15;
#define RING_INIT(I) xg##I = glab[(I) * VV]; xb##I = lg[(I) * VV];
  RING_INIT(0)  RING_INIT(1)  RING_INIT(2)  RING_INIT(3)
  RING_INIT(4)  RING_INIT(5)  RING_INIT(6)  RING_INIT(7)
  RING_INIT(8)  RING_INIT(9)  RING_INIT(10) RING_INIT(11)
  RING_INIT(12) RING_INIT(13) RING_INIT(14) RING_INIT(15)
#undef RING_INIT

  float a0, a1, a2;   // base-2 log-space alpha

  // ---- t = 0 ----
  {
    a0 = (lane == 0) ? xb0 * LOG2E : NEGF;
    a1 = (lane == 0) ? xg0 * LOG2E : NEGF;
    a2 = NEGF;
    xg0 = glab[16 * VV];
    xb0 = lg[16 * VV];
  }

  // ---- t = 1 .. len-1, macro-unrolled 16-step blocks (freeze via cndmask) ----
#define STEP(U, SLOT) { \
    const int t = tb_ + (U); \
    const float x0s = xb##SLOT * LOG2E; \
    const float xls = xg##SLOT * LOG2E; \
    int pf = t + 16; pf = pf > (TT - 1) ? (TT - 1) : pf; \
    xg##SLOT = glab[(size_t)pf * VV]; \
    xb##SLOT = lg[(size_t)pf * VV]; \
    const float a1p = \
        i2f(__builtin_amdgcn_update_dpp(f2i(NEGF), f2i(a1), 0x138, 0xF, 0xF, false)); \
    const float m  = fmaxf(fmaxf(a0, a1), a1p); \
    const float E0 = __builtin_amdgcn_exp2f(a0 - m); \
    const float E1 = __builtin_amdgcn_exp2f(a1 - m); \
    const float Ep = __builtin_amdgcn_exp2f(a1p - m); \
    float na0 = x0s + m + __builtin_amdgcn_logf(E0 + Ep); \
    float na1 = xls + m + __builtin_amdgcn_logf(E0 + E1 + (skip_ok ? Ep : 0.0f)); \
    float na2 = x0s + lae2_2(a2, a1); \
    na0 = fmaxf(na0, NEGF); \
    na1 = fmaxf(na1, NEGF); \
    const bool act = t < len; \
    a0 = act ? na0 : a0; \
    a1 = act ? na1 : a1; \
    a2 = act ? na2 : a2; \
  }

  for (int tb_ = 1; tb_ < len; tb_ += 16) {
    STEP(0, 1)   STEP(1, 2)   STEP(2, 3)   STEP(3, 4)
    STEP(4, 5)   STEP(5, 6)   STEP(6, 7)   STEP(7, 8)
    STEP(8, 9)   STEP(9, 10)  STEP(10, 11) STEP(11, 12)
    STEP(12, 13) STEP(13, 14) STEP(14, 15) STEP(15, 0)
  }
#undef STEP

  // ---- epilogue: loss = sumLse - ln2 * lae2_2(alpha[e], alpha[e-1]), e = 2*lab_len ----
  float ae, ae1;
  if (lab_len >= LL) {            // e = 128
    ae  = i2f(__builtin_amdgcn_readlane(f2i(a2), 63));
    ae1 = i2f(__builtin_amdgcn_readlane(f2i(a1), 63));
  } else if (lab_len >= 1) {      // e = 2*lab_len
    ae  = i2f(__builtin_amdgcn_readlane(f2i(a0), lab_len));
    ae1 = i2f(__builtin_amdgcn_readlane(f2i(a1), lab_len - 1));
  } else {
    ae  = i2f(__builtin_amdgcn_readlane(f2i(a0), 0));
    ae1 = ae;
  }
  float loss = sumLse - LN2 * lae2_2(ae, ae1);
  if (lab_len > len) loss = 0.0f;  // feasibility mask
  if (lane == 0) atomicAdd(out, loss * (1.0f / 256.0f));
}

extern "C" void kernel_launch(void* const* d_in, const int* in_sizes, int n_in,
                              void* d_out, int out_size, void* d_ws, size_t ws_size,
                              hipStream_t stream) {
  (void)in_sizes; (void)n_in; (void)out_size; (void)ws_size;
  const int* labels = (const int*)d_in[0];
  const float* logits = (const float*)d_in[1];
  const int* mask = (const int*)d_in[2];
  float* partials = (float*)d_ws;   // BB*16 floats; fully overwritten each call

  ctc_lse<<<dim3(BB * (TT / 64)), dim3(256), 0, stream>>>(logits, mask, partials, (float*)d_out);
  ctc_dp<<<dim3(BB), dim3(64), 0, stream>>>(labels, logits, mask, partials, (float*)d_out);
}

// Round 7
// 179.590 us; speedup vs baseline: 1.1271x; 1.1271x over previous
//
#include <hip/hip_runtime.h>

#define BB 256
#define TT 1024
#define VV 64
#define LL 64
#define NEGF  (-1e30f)
#define LOG2E 1.4426950408889634f
#define LN2   0.6931471805599453f

typedef __attribute__((address_space(1))) const void gas_t;  // global
typedef __attribute__((address_space(3))) void las_t;        // LDS

__device__ __forceinline__ int   f2i(float x) { return __float_as_int(x); }
__device__ __forceinline__ float i2f(int x)   { return __int_as_float(x); }

// base-2 logaddexp (hardware-native: v_exp_f32/v_log_f32 are 2^x / log2)
__device__ __forceinline__ float lae2_2(float a, float b) {
  float m = fmaxf(a, b);
  float d = fminf(a, b) - m;          // 0 if both equal (incl. both NEGF)
  return m + __builtin_amdgcn_logf(1.0f + __builtin_amdgcn_exp2f(d));
}

// ---------- Phase 1: per-block partial sums of log-sum-exp over valid t ----------
extern "C" __global__ void __launch_bounds__(256)
ctc_lse(const float* __restrict__ logits, const int* __restrict__ mask,
        float* __restrict__ partials, float* __restrict__ out) {
  const int bid = blockIdx.x;
  const int b   = bid >> 4;
  const int tb  = (bid & 15) << 6;
  const int tid = threadIdx.x;
  const int lane = tid & 63;
  const int w    = tid >> 6;

  if (bid == 0 && tid == 0) out[0] = 0.0f;   // d_out is re-poisoned before each call

  const float* lg = logits + (size_t)b * TT * VV;
  const int colv = (lane & 15) << 2;

  float acc = 0.0f;
#pragma unroll
  for (int p = 0; p < 4; ++p) {
    const int rowT = tb + (w << 4) + (p << 2) + (lane >> 4);
    const float4 v = *(const float4*)(lg + (size_t)rowT * VV + colv);
    float s = __expf(v.x) + __expf(v.y) + __expf(v.z) + __expf(v.w);
    s += __shfl_xor(s, 1);
    s += __shfl_xor(s, 2);
    s += __shfl_xor(s, 4);
    s += __shfl_xor(s, 8);             // 16-lane group sum -> row LSE argument
    if ((lane & 15) == 0) {
      const int mv = mask[b * TT + rowT];   // prefix-true: mv!=0 <=> t < len
      acc += mv ? __logf(s) : 0.0f;
    }
  }
  acc = ((lane & 15) == 0) ? acc : 0.0f;
  acc += __shfl_xor(acc, 16);
  acc += __shfl_xor(acc, 32);

  __shared__ float wsum[4];
  if (lane == 0) wsum[w] = acc;
  __syncthreads();
  if (tid == 0) partials[bid] = wsum[0] + wsum[1] + wsum[2] + wsum[3];
}

// ---------- Phase 2: sequential alpha DP on RAW logits, base-2 log space ----------
// One wave per b. Lane l holds alpha[2l] (a0), alpha[2l+1] (a1); lane63 also
// alpha[128] (a2). Logit rows staged through a 4-window LDS ring filled by
// global_load_lds DMA (width 16B: 4 instrs/window). LDS is mutable memory, so
// the per-window ds_reads into 32 named VGPRs can be neither rematerialized
// nor sunk past the next window's DMA issue — the prefetch distance the
// compiler kept destroying in rounds 3-5 is now structurally enforced.
extern "C" __global__ void __launch_bounds__(64, 1)
ctc_dp(const int* __restrict__ labels, const float* __restrict__ logits,
       const int* __restrict__ mask, const float* __restrict__ partials,
       float* __restrict__ out) {
  __shared__ float ring[4 * 16 * VV];                    // 4 windows x 16 rows, 16 KB
  const int b = blockIdx.x;
  const int lane = threadIdx.x;

  const int lab = labels[b * LL + lane];                 // label for state 2*lane+1
  const int lab_len = (int)__popcll(__ballot(lab != 0));

  // sum of per-block LSE partials for this b (16 slots)
  float psum = (lane < 16) ? partials[(b << 4) + lane] : 0.0f;
  psum += __shfl_xor(psum, 1);
  psum += __shfl_xor(psum, 2);
  psum += __shfl_xor(psum, 4);
  psum += __shfl_xor(psum, 8);
  const float sumLse = i2f(__builtin_amdgcn_readfirstlane(f2i(psum)));

  // logits_len = popcount of prefix-true mask row
  int lsum = 0;
  const int* mrow = mask + b * TT;
#pragma unroll
  for (int k = 0; k < TT / 64; ++k) lsum += mrow[lane + (k << 6)];
#pragma unroll
  for (int off = 32; off; off >>= 1) lsum += __shfl_xor(lsum, off);
  int len = __builtin_amdgcn_readfirstlane(lsum);
  len = len < 1 ? 1 : (len > TT ? TT : len);

  // allow_skip for odd state: lab != 0 && lab != prev lab
  const int plab = __builtin_amdgcn_update_dpp(0, lab, 0x138, 0xF, 0xF, false); // wave_shr:1
  const bool skip_ok = (lab != 0) && (lab != plab);

  const float* lg = logits + (size_t)b * TT * VV;

  // DMA window W (rows [16W,16W+16)) into ring slot W&3: 4 x 1KB (16B/lane).
#define DMA_WIN(W) { \
    const int we = (W) > 63 ? 63 : (W); \
    const float* gp = lg + (we << 10) + (lane << 2); \
    float* lp = ring + ((we & 3) << 10); \
    __builtin_amdgcn_global_load_lds((gas_t*)(gp), (las_t*)(lp), 16, 0, 0); \
    __builtin_amdgcn_global_load_lds((gas_t*)(gp + 256), (las_t*)(lp + 256), 16, 0, 0); \
    __builtin_amdgcn_global_load_lds((gas_t*)(gp + 512), (las_t*)(lp + 512), 16, 0, 0); \
    __builtin_amdgcn_global_load_lds((gas_t*)(gp + 768), (las_t*)(lp + 768), 16, 0, 0); \
  }
  DMA_WIN(0)
  DMA_WIN(1)
  DMA_WIN(2)

  // t=0 is executed as a normal step: with a0=(lane0?0:NEGF), a1=a2=NEGF the
  // recurrence yields exactly a0=x0, a1=xl on lane0 and NEGF elsewhere
  // (|logit| << ulp(1e30) so the dead-lane arithmetic collapses to NEGF).
  float a0 = (lane == 0) ? 0.0f : NEGF;
  float a1 = NEGF;
  float a2 = NEGF;

#define STEP(U) { \
    const int t = w16 + (U); \
    const float x0s = c##U * LOG2E; \
    const float xls = g##U * LOG2E; \
    const float a1p = \
        i2f(__builtin_amdgcn_update_dpp(f2i(NEGF), f2i(a1), 0x138, 0xF, 0xF, false)); \
    const float m  = fmaxf(fmaxf(a0, a1), a1p); \
    const float E0 = __builtin_amdgcn_exp2f(a0 - m); \
    const float E1 = __builtin_amdgcn_exp2f(a1 - m); \
    const float Ep = __builtin_amdgcn_exp2f(a1p - m); \
    float na0 = x0s + m + __builtin_amdgcn_logf(E0 + Ep); \
    float na1 = xls + m + __builtin_amdgcn_logf(E0 + E1 + (skip_ok ? Ep : 0.0f)); \
    float na2 = x0s + lae2_2(a2, a1); \
    na0 = fmaxf(na0, NEGF); \
    na1 = fmaxf(na1, NEGF); \
    const bool act = t < len; \
    a0 = act ? na0 : a0; \
    a1 = act ? na1 : a1; \
    a2 = act ? na2 : a2; \
  }

  for (int w16 = 0, w = 0; w16 < len; w16 += 16, ++w) {
    // All DMAs issued before the previous window's compute have landed; the
    // youngest in-flight DMA is >= one full window (~900 cyc) old -> ~free.
    __builtin_amdgcn_s_waitcnt(0);
    const float* rb = ring + ((w & 3) << 10);
    // Window values -> 32 named VGPRs. Gathers: banks (lab%32), <=2 distinct
    // addresses/bank (lab, lab+32) -> conflict-free; blanks: broadcast.
    float g0, g1, g2, g3, g4, g5, g6, g7, g8, g9, g10, g11, g12, g13, g14, g15;
    float c0, c1, c2, c3, c4, c5, c6, c7, c8, c9, c10, c11, c12, c13, c14, c15;
#define RD(U) g##U = rb[((U) << 6) + lab]; c##U = rb[(U) << 6];
    RD(0)  RD(1)  RD(2)  RD(3)  RD(4)  RD(5)  RD(6)  RD(7)
    RD(8)  RD(9)  RD(10) RD(11) RD(12) RD(13) RD(14) RD(15)
#undef RD
    DMA_WIN(w + 3)      // pins the ds_reads above; lands before window w+3
    STEP(0)  STEP(1)  STEP(2)  STEP(3)  STEP(4)  STEP(5)  STEP(6)  STEP(7)
    STEP(8)  STEP(9)  STEP(10) STEP(11) STEP(12) STEP(13) STEP(14) STEP(15)
  }
#undef STEP
#undef DMA_WIN

  // Drain in-flight DMAs: an LDS write landing after endpgm could corrupt a
  // successor workgroup's LDS in this slot.
  __builtin_amdgcn_s_waitcnt(0);

  // ---- epilogue: loss = sumLse - ln2 * lae2_2(alpha[e], alpha[e-1]), e = 2*lab_len ----
  float ae, ae1;
  if (lab_len >= LL) {            // e = 128
    ae  = i2f(__builtin_amdgcn_readlane(f2i(a2), 63));
    ae1 = i2f(__builtin_amdgcn_readlane(f2i(a1), 63));
  } else if (lab_len >= 1) {      // e = 2*lab_len
    ae  = i2f(__builtin_amdgcn_readlane(f2i(a0), lab_len));
    ae1 = i2f(__builtin_amdgcn_readlane(f2i(a1), lab_len - 1));
  } else {
    ae  = i2f(__builtin_amdgcn_readlane(f2i(a0), 0));
    ae1 = ae;
  }
  float loss = sumLse - LN2 * lae2_2(ae, ae1);
  if (lab_len > len) loss = 0.0f;  // feasibility mask
  if (lane == 0) atomicAdd(out, loss * (1.0f / 256.0f));
}

extern "C" void kernel_launch(void* const* d_in, const int* in_sizes, int n_in,
                              void* d_out, int out_size, void* d_ws, size_t ws_size,
                              hipStream_t stream) {
  (void)in_sizes; (void)n_in; (void)out_size; (void)ws_size;
  const int* labels = (const int*)d_in[0];
  const float* logits = (const float*)d_in[1];
  const int* mask = (const int*)d_in[2];
  float* partials = (float*)d_ws;   // BB*16 floats; fully overwritten each call

  ctc_lse<<<dim3(BB * (TT / 64)), dim3(256), 0, stream>>>(logits, mask, partials, (float*)d_out);
  ctc_dp<<<dim3(BB), dim3(64), 0, stream>>>(labels, logits, mask, partials, (float*)d_out);
}

// Round 8
// 162.069 us; speedup vs baseline: 1.2490x; 1.1081x over previous
//
#include <hip/hip_runtime.h>

#define BB 256
#define TT 1024
#define VV 64
#define LL 64
#define NEGF  (-1e30f)
#define LOG2E 1.4426950408889634f
#define LN2   0.6931471805599453f

typedef __attribute__((address_space(1))) const void gas_t;  // global
typedef __attribute__((address_space(3))) void las_t;        // LDS

__device__ __forceinline__ int   f2i(float x) { return __float_as_int(x); }
__device__ __forceinline__ float i2f(int x)   { return __int_as_float(x); }

// base-2 logaddexp (hardware-native v_exp_f32/v_log_f32 are 2^x / log2)
__device__ __forceinline__ float lae2_2(float a, float b) {
  float m = fmaxf(a, b);
  float d = fminf(a, b) - m;          // 0 if both equal (incl. both NEGF)
  return m + __builtin_amdgcn_logf(1.0f + __builtin_amdgcn_exp2f(d));
}

// ---------- Fused kernel: block b handles batch element b ----------
// Waves 1-3: sumLse over valid t (runs concurrently on other SIMDs, fully
// hidden under the DP). Wave 0: the sequential alpha DP through a 4-window
// LDS ring filled by global_load_lds DMA (round-7 structure, which finally
// made the prefetch unremovable: VGPR 28->68, 108->85us). One barrier joins.
extern "C" __global__ void __launch_bounds__(256, 1)
ctc_fused(const int* __restrict__ labels, const float* __restrict__ logits,
          const int* __restrict__ mask, float* __restrict__ out) {
  __shared__ float ring[4 * 16 * VV];   // 16 KB, wave0's staging ring
  __shared__ float lsePart[3];
  const int b = blockIdx.x;
  const int tid = threadIdx.x;
  const int lane = tid & 63;
  const int wv = tid >> 6;

  const float* lg = logits + (size_t)b * TT * VV;

  if (wv != 0) {
    // ---- waves 1-3: partial sums of log-sum-exp over this b's valid rows ----
    const int colv = (lane & 15) << 2;
    float acc = 0.0f;
    for (int p = wv - 1; p < 256; p += 3) {       // 4 rows per pass, 1KB coalesced
      const int rowT = (p << 2) + (lane >> 4);
      const float4 v = *(const float4*)(lg + (size_t)rowT * VV + colv);
      float s = __expf(v.x) + __expf(v.y) + __expf(v.z) + __expf(v.w);
      s += __shfl_xor(s, 1);
      s += __shfl_xor(s, 2);
      s += __shfl_xor(s, 4);
      s += __shfl_xor(s, 8);                      // 16-lane row sum
      if ((lane & 15) == 0) {
        const int mv = mask[b * TT + rowT];       // prefix-true mask
        acc += mv ? __logf(s) : 0.0f;
      }
    }
    acc = ((lane & 15) == 0) ? acc : 0.0f;
    acc += __shfl_xor(acc, 16);
    acc += __shfl_xor(acc, 32);
    if (lane == 0) lsePart[wv - 1] = acc;
  } else {
    // ---- wave 0: the DP (base-2 log space, raw logits) ----
    // DMA first 3 windows immediately; preamble overlaps their flight.
#define DMA_WIN(W) { \
    const int we = (W) > 63 ? 63 : (W); \
    const float* gp = lg + (we << 10) + (lane << 2); \
    float* lp = ring + ((we & 3) << 10); \
    __builtin_amdgcn_global_load_lds((gas_t*)(gp), (las_t*)(lp), 16, 0, 0); \
    __builtin_amdgcn_global_load_lds((gas_t*)(gp + 256), (las_t*)(lp + 256), 16, 0, 0); \
    __builtin_amdgcn_global_load_lds((gas_t*)(gp + 512), (las_t*)(lp + 512), 16, 0, 0); \
    __builtin_amdgcn_global_load_lds((gas_t*)(gp + 768), (las_t*)(lp + 768), 16, 0, 0); \
  }
    DMA_WIN(0)
    DMA_WIN(1)
    DMA_WIN(2)

    const int lab = labels[b * LL + lane];        // label for state 2*lane+1
    const int lab_len = (int)__popcll(__ballot(lab != 0));

    int lsum = 0;
    const int* mrow = mask + b * TT;
#pragma unroll
    for (int k = 0; k < TT / 64; ++k) lsum += mrow[lane + (k << 6)];
#pragma unroll
    for (int off = 32; off; off >>= 1) lsum += __shfl_xor(lsum, off);
    int len = __builtin_amdgcn_readfirstlane(lsum);
    len = len < 1 ? 1 : (len > TT ? TT : len);

    const int plab = __builtin_amdgcn_update_dpp(0, lab, 0x138, 0xF, 0xF, false);
    const float sk = (lab != 0 && lab != plab) ? 1.0f : 0.0f;   // allow_skip

    // t=0 runs as a normal step from this init (verified exact in fp32).
    float a0 = (lane == 0) ? 0.0f : NEGF;
    float a1 = NEGF;
    float a2 = NEGF;

    // No NEGF clamps needed: na1's LSE sum >= 1 (its max is among its args) so
    // a1 never reaches -inf; a -inf in a0 is absorbed (exp2(-inf-finite)=0)
    // and all-three--inf (the NaN case) is unreachable since a1 stays finite
    // at any live/dead boundary.
#define STEP_CORE(U) \
    const float x0s = c##U * LOG2E; \
    const float xls = g##U * LOG2E; \
    const float a1p = \
        i2f(__builtin_amdgcn_update_dpp(f2i(NEGF), f2i(a1), 0x138, 0xF, 0xF, false)); \
    const float m  = fmaxf(fmaxf(a0, a1), a1p); \
    const float E0 = __builtin_amdgcn_exp2f(a0 - m); \
    const float E1 = __builtin_amdgcn_exp2f(a1 - m); \
    const float Ep = __builtin_amdgcn_exp2f(a1p - m); \
    const float s01 = E0 + E1; \
    const float na0 = x0s + m + __builtin_amdgcn_logf(E0 + Ep); \
    const float na2 = x0s + lae2_2(a2, a1); \
    const float na1 = xls + m + __builtin_amdgcn_logf(fmaf(sk, Ep, s01));

#define STEP_F(U) { STEP_CORE(U) a0 = na0; a1 = na1; a2 = na2; }
#define STEP_R(U) { STEP_CORE(U) \
    const bool act = (w16 + (U)) < len; \
    a0 = act ? na0 : a0; a1 = act ? na1 : a1; a2 = act ? na2 : a2; }

#define RD(U) g##U = rb[((U) << 6) + lab]; c##U = rb[(U) << 6];

    int w = 0;
    int w16 = 0;
    for (; w16 + 16 <= len; w16 += 16, ++w) {
      __builtin_amdgcn_s_waitcnt(0);    // youngest in-flight DMA is >=1 window old
      const float* rb = ring + ((w & 3) << 10);
      float g0, g1, g2, g3, g4, g5, g6, g7, g8, g9, g10, g11, g12, g13, g14, g15;
      float c0, c1, c2, c3, c4, c5, c6, c7, c8, c9, c10, c11, c12, c13, c14, c15;
      RD(0)  RD(1)  RD(2)  RD(3)  RD(4)  RD(5)  RD(6)  RD(7)
      RD(8)  RD(9)  RD(10) RD(11) RD(12) RD(13) RD(14) RD(15)
      DMA_WIN(w + 3)                    // pins the ds_reads; lands before use
      STEP_F(0)  STEP_F(1)  STEP_F(2)  STEP_F(3)
      STEP_F(4)  STEP_F(5)  STEP_F(6)  STEP_F(7)
      STEP_F(8)  STEP_F(9)  STEP_F(10) STEP_F(11)
      STEP_F(12) STEP_F(13) STEP_F(14) STEP_F(15)
    }
    if (w16 < len) {                    // ragged final window (freeze via cndmask)
      __builtin_amdgcn_s_waitcnt(0);
      const float* rb = ring + ((w & 3) << 10);
      float g0, g1, g2, g3, g4, g5, g6, g7, g8, g9, g10, g11, g12, g13, g14, g15;
      float c0, c1, c2, c3, c4, c5, c6, c7, c8, c9, c10, c11, c12, c13, c14, c15;
      RD(0)  RD(1)  RD(2)  RD(3)  RD(4)  RD(5)  RD(6)  RD(7)
      RD(8)  RD(9)  RD(10) RD(11) RD(12) RD(13) RD(14) RD(15)
      STEP_R(0)  STEP_R(1)  STEP_R(2)  STEP_R(3)
      STEP_R(4)  STEP_R(5)  STEP_R(6)  STEP_R(7)
      STEP_R(8)  STEP_R(9)  STEP_R(10) STEP_R(11)
      STEP_R(12) STEP_R(13) STEP_R(14) STEP_R(15)
    }
    __builtin_amdgcn_s_waitcnt(0);      // drain DMAs before LDS slot reuse

    // stash DP results for the post-barrier epilogue in registers (wave-local)
    float ae, ae1;
    if (lab_len >= LL) {            // e = 128
      ae  = i2f(__builtin_amdgcn_readlane(f2i(a2), 63));
      ae1 = i2f(__builtin_amdgcn_readlane(f2i(a1), 63));
    } else if (lab_len >= 1) {      // e = 2*lab_len
      ae  = i2f(__builtin_amdgcn_readlane(f2i(a0), lab_len));
      ae1 = i2f(__builtin_amdgcn_readlane(f2i(a1), lab_len - 1));
    } else {
      ae  = i2f(__builtin_amdgcn_readlane(f2i(a0), 0));
      ae1 = ae;
    }
    // a0/a1 reuse below barrier not needed; carry ae/ae1 via a0/a1
    a0 = ae; a1 = ae1;
    // fallthrough to barrier
    __syncthreads();                    // join with waves 1-3
    float loss = (lsePart[0] + lsePart[1] + lsePart[2]) - LN2 * lae2_2(a0, a1);
    if (lab_len > len) loss = 0.0f;     // feasibility mask
    if (lane == 0) atomicAdd(out, loss * (1.0f / 256.0f));
    return;
#undef STEP_CORE
#undef STEP_F
#undef STEP_R
#undef RD
#undef DMA_WIN
  }
  __syncthreads();                      // waves 1-3 join here
}

extern "C" void kernel_launch(void* const* d_in, const int* in_sizes, int n_in,
                              void* d_out, int out_size, void* d_ws, size_t ws_size,
                              hipStream_t stream) {
  (void)in_sizes; (void)n_in; (void)out_size; (void)d_ws; (void)ws_size;
  hipMemsetAsync(d_out, 0, sizeof(float), stream);   // d_out is poisoned 0xAA
  ctc_fused<<<dim3(BB), dim3(256), 0, stream>>>(
      (const int*)d_in[0], (const float*)d_in[1], (const int*)d_in[2], (float*)d_out);
}

// Round 9
// 156.687 us; speedup vs baseline: 1.2919x; 1.0344x over previous
//
#include <hip/hip_runtime.h>

#define BB 256
#define TT 1024
#define VV 64
#define LL 64
#define NEGF  (-1e30f)
#define LOG2E 1.4426950408889634f
#define LN2   0.6931471805599453f

typedef __attribute__((address_space(1))) const void gas_t;  // global
typedef __attribute__((address_space(3))) void las_t;        // LDS

__device__ __forceinline__ int   f2i(float x) { return __float_as_int(x); }
__device__ __forceinline__ float i2f(int x)   { return __int_as_float(x); }

// wave-wide max of non-negative values (0 is the identity), result broadcast
__device__ __forceinline__ float wave_max63(float x) {
  x = fmaxf(x, i2f(__builtin_amdgcn_update_dpp(0, f2i(x), 0x111, 0xF, 0xF, true)));
  x = fmaxf(x, i2f(__builtin_amdgcn_update_dpp(0, f2i(x), 0x112, 0xF, 0xF, true)));
  x = fmaxf(x, i2f(__builtin_amdgcn_update_dpp(0, f2i(x), 0x114, 0xF, 0xF, true)));
  x = fmaxf(x, i2f(__builtin_amdgcn_update_dpp(0, f2i(x), 0x118, 0xF, 0xF, true)));
  x = fmaxf(x, i2f(__builtin_amdgcn_update_dpp(0, f2i(x), 0x142, 0xF, 0xF, true)));
  x = fmaxf(x, i2f(__builtin_amdgcn_update_dpp(0, f2i(x), 0x143, 0xF, 0xF, true)));
  return i2f(__builtin_amdgcn_readlane(f2i(x), 63));
}

// ---------- Fused kernel: block b handles batch element b ----------
// Waves 1-3: sumLse over valid t (other SIMDs, hidden under the DP).
// Wave 0: LINEAR-SPACE alpha DP — A_{t+1}[s] = em[s]*(A[s]+A[s-1]+sk*A[s-2]).
// No transcendentals on the recurrence chain (rounds 7/8 proved the log-space
// chain is exp/log dependent-latency-bound at ~205 cyc/step). Dynamic range
// handled by once-per-window renorm to 2^60 via exponent-bit surgery with an
// integer log2 correction (ctot). States >~145 nats below the running max
// get truncated — contributes < e^-145 relative to the loss (threshold 45.76).
extern "C" __global__ void __launch_bounds__(256, 1)
ctc_fused(const int* __restrict__ labels, const float* __restrict__ logits,
          const int* __restrict__ mask, float* __restrict__ out) {
  __shared__ float ring[4 * 16 * VV];   // 16 KB staging ring for wave 0
  __shared__ float lsePart[3];
  const int b = blockIdx.x;
  const int tid = threadIdx.x;
  const int lane = tid & 63;
  const int wv = tid >> 6;

  const float* lg = logits + (size_t)b * TT * VV;

  if (wv != 0) {
    // ---- waves 1-3: partial sums of log-sum-exp over this b's valid rows ----
    const int colv = (lane & 15) << 2;
    float acc = 0.0f;
    for (int p = wv - 1; p < 256; p += 3) {       // 4 rows per pass, 1KB coalesced
      const int rowT = (p << 2) + (lane >> 4);
      const float4 v = *(const float4*)(lg + (size_t)rowT * VV + colv);
      float s = __expf(v.x) + __expf(v.y) + __expf(v.z) + __expf(v.w);
      s += __shfl_xor(s, 1);
      s += __shfl_xor(s, 2);
      s += __shfl_xor(s, 4);
      s += __shfl_xor(s, 8);                      // 16-lane row sum
      if ((lane & 15) == 0) {
        const int mv = mask[b * TT + rowT];       // prefix-true mask
        acc += mv ? __logf(s) : 0.0f;
      }
    }
    acc = ((lane & 15) == 0) ? acc : 0.0f;
    acc += __shfl_xor(acc, 16);
    acc += __shfl_xor(acc, 32);
    if (lane == 0) lsePart[wv - 1] = acc;
  } else {
    // ---- wave 0: linear-space DP ----
#define DMA_WIN(W) { \
    const int we = (W) > 63 ? 63 : (W); \
    const float* gp = lg + (we << 10) + (lane << 2); \
    float* lp = ring + ((we & 3) << 10); \
    __builtin_amdgcn_global_load_lds((gas_t*)(gp), (las_t*)(lp), 16, 0, 0); \
    __builtin_amdgcn_global_load_lds((gas_t*)(gp + 256), (las_t*)(lp + 256), 16, 0, 0); \
    __builtin_amdgcn_global_load_lds((gas_t*)(gp + 512), (las_t*)(lp + 512), 16, 0, 0); \
    __builtin_amdgcn_global_load_lds((gas_t*)(gp + 768), (las_t*)(lp + 768), 16, 0, 0); \
  }
    DMA_WIN(0)
    DMA_WIN(1)
    DMA_WIN(2)

    const int lab = labels[b * LL + lane];        // label for state 2*lane+1
    const int lab_len = (int)__popcll(__ballot(lab != 0));

    int lsum = 0;
    const int* mrow = mask + b * TT;
#pragma unroll
    for (int k = 0; k < TT / 64; ++k) lsum += mrow[lane + (k << 6)];
#pragma unroll
    for (int off = 32; off; off >>= 1) lsum += __shfl_xor(lsum, off);
    int len = __builtin_amdgcn_readfirstlane(lsum);
    len = len < 1 ? 1 : (len > TT ? TT : len);

    const int plab = __builtin_amdgcn_update_dpp(0, lab, 0x138, 0xF, 0xF, false);
    const float sk = (lab != 0 && lab != plab) ? 1.0f : 0.0f;   // allow_skip

    // t=0 runs as a normal step from A=(lane0 ? 1 : 0): yields A0=em_c, A1=em_g
    // on lane 0 and 0 elsewhere — exact. A2 (state 128, lane63) starts 0; its
    // value on lanes!=63 is a harmless phantom with the same dynamics (it is
    // included in the renorm max, which only shifts the tracked scale).
    float A0 = (lane == 0) ? 1.0f : 0.0f;
    float A1 = 0.0f;
    float A2 = 0.0f;
    int ctot = 0;                                  // A_stored = A_true * 2^ctot

    // per-window renorm: scale so wave-max -> ~2^60, track log2 in ctot.
#define RENORM() { \
    const float mxv = wave_max63(fmaxf(fmaxf(A0, A1), A2)); \
    const int eb = (f2i(mxv) >> 23) & 255; \
    int kk = (eb > 0 && eb < 255) ? (187 - eb) : 0; \
    kk = kk > 126 ? 126 : (kk < -126 ? -126 : kk); \
    ctot += kk; \
    const float sc = i2f((127 + kk) << 23); \
    A0 *= sc; A1 *= sc; A2 *= sc; \
  }

#define STEP_F(U) { \
    const float A1p = i2f(__builtin_amdgcn_update_dpp(0, f2i(A1), 0x138, 0xF, 0xF, false)); \
    const float nA0 = c##U * (A0 + A1p); \
    const float nA1 = g##U * fmaf(sk, A1p, A0 + A1); \
    const float nA2 = c##U * (A2 + A1); \
    A0 = nA0; A1 = nA1; A2 = nA2; \
  }
#define STEP_R(U) { \
    const float A1p = i2f(__builtin_amdgcn_update_dpp(0, f2i(A1), 0x138, 0xF, 0xF, false)); \
    const float nA0 = c##U * (A0 + A1p); \
    const float nA1 = g##U * fmaf(sk, A1p, A0 + A1); \
    const float nA2 = c##U * (A2 + A1); \
    const bool act = (w16 + (U)) < len; \
    A0 = act ? nA0 : A0; A1 = act ? nA1 : A1; A2 = act ? nA2 : A2; \
  }
    // window read + convert to linear emissions (off the recurrence chain)
#define RD(U) g##U = __builtin_amdgcn_exp2f(rb[((U) << 6) + lab] * LOG2E); \
              c##U = __builtin_amdgcn_exp2f(rb[(U) << 6] * LOG2E);

    int w = 0;
    int w16 = 0;
    for (; w16 + 16 <= len; w16 += 16, ++w) {
      __builtin_amdgcn_s_waitcnt(0);    // youngest in-flight DMA is >=1 window old
      const float* rb = ring + ((w & 3) << 10);
      RENORM()
      float g0, g1, g2, g3, g4, g5, g6, g7, g8, g9, g10, g11, g12, g13, g14, g15;
      float c0, c1, c2, c3, c4, c5, c6, c7, c8, c9, c10, c11, c12, c13, c14, c15;
      RD(0)  RD(1)  RD(2)  RD(3)  RD(4)  RD(5)  RD(6)  RD(7)
      RD(8)  RD(9)  RD(10) RD(11) RD(12) RD(13) RD(14) RD(15)
      DMA_WIN(w + 3)                    // pins the ds_reads; lands before use
      STEP_F(0)  STEP_F(1)  STEP_F(2)  STEP_F(3)
      STEP_F(4)  STEP_F(5)  STEP_F(6)  STEP_F(7)
      STEP_F(8)  STEP_F(9)  STEP_F(10) STEP_F(11)
      STEP_F(12) STEP_F(13) STEP_F(14) STEP_F(15)
    }
    if (w16 < len) {                    // ragged final window (freeze via cndmask)
      __builtin_amdgcn_s_waitcnt(0);
      const float* rb = ring + ((w & 3) << 10);
      RENORM()
      float g0, g1, g2, g3, g4, g5, g6, g7, g8, g9, g10, g11, g12, g13, g14, g15;
      float c0, c1, c2, c3, c4, c5, c6, c7, c8, c9, c10, c11, c12, c13, c14, c15;
      RD(0)  RD(1)  RD(2)  RD(3)  RD(4)  RD(5)  RD(6)  RD(7)
      RD(8)  RD(9)  RD(10) RD(11) RD(12) RD(13) RD(14) RD(15)
      STEP_R(0)  STEP_R(1)  STEP_R(2)  STEP_R(3)
      STEP_R(4)  STEP_R(5)  STEP_R(6)  STEP_R(7)
      STEP_R(8)  STEP_R(9)  STEP_R(10) STEP_R(11)
      STEP_R(12) STEP_R(13) STEP_R(14) STEP_R(15)
    }
    __builtin_amdgcn_s_waitcnt(0);      // drain DMAs before LDS slot reuse

    // epilogue values: e = 2*lab_len
    float ae, ae1;
    if (lab_len >= LL) {            // e = 128
      ae  = i2f(__builtin_amdgcn_readlane(f2i(A2), 63));
      ae1 = i2f(__builtin_amdgcn_readlane(f2i(A1), 63));
    } else if (lab_len >= 1) {      // e = 2*lab_len
      ae  = i2f(__builtin_amdgcn_readlane(f2i(A0), lab_len));
      ae1 = i2f(__builtin_amdgcn_readlane(f2i(A1), lab_len - 1));
    } else {
      ae  = i2f(__builtin_amdgcn_readlane(f2i(A0), 0));
      ae1 = ae;
    }
    const float se = ae + ae1;          // linear-space logaddexp
    __syncthreads();                    // join with waves 1-3
    float loss = (lsePart[0] + lsePart[1] + lsePart[2])
               - LN2 * (__builtin_amdgcn_logf(se) - (float)ctot);
    if (lab_len > len) loss = 0.0f;     // feasibility mask
    if (lane == 0) atomicAdd(out, loss * (1.0f / 256.0f));
    return;
#undef STEP_F
#undef STEP_R
#undef RD
#undef RENORM
#undef DMA_WIN
  }
  __syncthreads();                      // waves 1-3 join here
}

extern "C" void kernel_launch(void* const* d_in, const int* in_sizes, int n_in,
                              void* d_out, int out_size, void* d_ws, size_t ws_size,
                              hipStream_t stream) {
  (void)in_sizes; (void)n_in; (void)out_size; (void)d_ws; (void)ws_size;
  hipMemsetAsync(d_out, 0, sizeof(float), stream);   // d_out is poisoned 0xAA
  ctc_fused<<<dim3(BB), dim3(256), 0, stream>>>(
      (const int*)d_in[0], (const float*)d_in[1], (const int*)d_in[2], (float*)d_out);
}

// Round 11
// 142.954 us; speedup vs baseline: 1.4160x; 1.0961x over previous
//
#include <hip/hip_runtime.h>

#define BB 256
#define TT 1024
#define VV 64
#define LL 64
#define LOG2E 1.4426950408889634f
#define LN2   0.6931471805599453f

__device__ __forceinline__ int   f2i(float x) { return __float_as_int(x); }
__device__ __forceinline__ float i2f(int x)   { return __int_as_float(x); }

// lgkm-only barrier: orders LDS producer->consumer WITHOUT draining vmcnt,
// so producer global prefetch loads stay in flight across windows. The
// "memory" clobber is a compiler fence (pins loads/stores on both sides).
__device__ __forceinline__ void barrier_lds() {
  asm volatile("s_waitcnt lgkmcnt(0)" ::: "memory");
  __builtin_amdgcn_s_barrier();
}

// wave-wide max of non-negative values (0 identity), result broadcast
__device__ __forceinline__ float wave_max63(float x) {
  x = fmaxf(x, i2f(__builtin_amdgcn_update_dpp(0, f2i(x), 0x111, 0xF, 0xF, true)));
  x = fmaxf(x, i2f(__builtin_amdgcn_update_dpp(0, f2i(x), 0x112, 0xF, 0xF, true)));
  x = fmaxf(x, i2f(__builtin_amdgcn_update_dpp(0, f2i(x), 0x114, 0xF, 0xF, true)));
  x = fmaxf(x, i2f(__builtin_amdgcn_update_dpp(0, f2i(x), 0x118, 0xF, 0xF, true)));
  x = fmaxf(x, i2f(__builtin_amdgcn_update_dpp(0, f2i(x), 0x142, 0xF, 0xF, true)));
  x = fmaxf(x, i2f(__builtin_amdgcn_update_dpp(0, f2i(x), 0x143, 0xF, 0xF, true)));
  return i2f(__builtin_amdgcn_readlane(f2i(x), 63));
}

// ---------- Fused producer/consumer kernel: block b = batch element b ----------
// Waves 1-3 (producers): stream logit rows, convert to LINEAR emissions e^x,
// ds_write into a 2-window LDS double buffer; the same values give the row
// LSE sums. Global loads are register-prefetched one window ahead (pinned by
// the barrier). Wave 0 (consumer): linear-space DP, zero vmem in its loop ->
// no vmcnt drains. Renorm target 2^60 (kk=187-eb): R9-validated; R10's 2^20
// target flushed far-below-max end states to 0 -> log(0) = -inf (the R10 inf).
extern "C" __global__ void __launch_bounds__(256, 1)
ctc_fused(const int* __restrict__ labels, const float* __restrict__ logits,
          const int* __restrict__ mask, float* __restrict__ out) {
  __shared__ float buf[2][16][VV];      // 8 KB: 2 windows x 16 rows x 64 vocab
  __shared__ float lsePart[3];
  const int b = blockIdx.x;
  const int tid = threadIdx.x;
  const int lane = tid & 63;
  const int wv = tid >> 6;

  const float* lg = logits + (size_t)b * TT * VV;

  // every wave computes len (redundant, preamble-only)
  int lsum = 0;
  const int* mrow = mask + b * TT;
#pragma unroll
  for (int k = 0; k < TT / 64; ++k) lsum += mrow[lane + (k << 6)];
#pragma unroll
  for (int off = 32; off; off >>= 1) lsum += __shfl_xor(lsum, off);
  int len = __builtin_amdgcn_readfirstlane(lsum);
  len = len < 1 ? 1 : (len > TT ? TT : len);

  // wave-0-only DP state
  int lab = 0, lab_len = 0;
  float sk = 0.0f;
  float A0 = 0.0f, A1 = 0.0f, A2 = 0.0f;
  int ctot = 0;
  if (wv == 0) {
    lab = labels[b * LL + lane] & 63;             // label for state 2*lane+1
    lab_len = (int)__popcll(__ballot(lab != 0));
    const int plab = __builtin_amdgcn_update_dpp(0, lab, 0x138, 0xF, 0xF, false);
    sk = (lab != 0 && lab != plab) ? 1.0f : 0.0f; // allow_skip
    A0 = (lane == 0) ? 1.0f : 0.0f;               // t=0 runs as a normal step
  }

  // producer geometry: row-group rg in [0,4); wave wv covers rows (wv-1)*4+rg,
  // wave 1 additionally rows 12+rg. 16 lanes x float4 per row.
  const int rg = lane >> 4;
  const int colv = (lane & 15) << 2;
  const int r0 = ((wv - 1) << 2) + rg;
  const bool has2 = (wv == 1);
  const int r1 = 12 + rg;
  float acc = 0.0f;

  float4 pa0 = {0, 0, 0, 0}, pa1 = {0, 0, 0, 0};
  float4 pb0 = {0, 0, 0, 0}, pb1 = {0, 0, 0, 0};

#define PLOAD(W, R) (*(const float4*)(lg + (size_t)((((W) << 4) + (R)) * VV) + colv))

#define EMIT(W, R, V) { \
    const float e0 = __builtin_amdgcn_exp2f((V).x * LOG2E); \
    const float e1 = __builtin_amdgcn_exp2f((V).y * LOG2E); \
    const float e2 = __builtin_amdgcn_exp2f((V).z * LOG2E); \
    const float e3 = __builtin_amdgcn_exp2f((V).w * LOG2E); \
    float4 ev; ev.x = e0; ev.y = e1; ev.z = e2; ev.w = e3; \
    *(float4*)&buf[(W) & 1][R][colv] = ev; \
    float s = (e0 + e1) + (e2 + e3); \
    s += __shfl_xor(s, 1); s += __shfl_xor(s, 2); \
    s += __shfl_xor(s, 4); s += __shfl_xor(s, 8); \
    if ((lane & 15) == 0 && ((((W) << 4) + (R)) < len)) acc += __logf(s); \
  }

  // renorm to 2^60 (R9-validated): flush floor ~186 log2 below running max,
  // overflow headroom +67 log2 per window.
#define RENORM() { \
    const float mxv = wave_max63(fmaxf(fmaxf(A0, A1), A2)); \
    const int eb = (f2i(mxv) >> 23) & 255; \
    int kk = (eb > 0 && eb < 255) ? (187 - eb) : 0; \
    kk = kk > 126 ? 126 : (kk < -126 ? -126 : kk); \
    ctot += kk; \
    const float sc = i2f((127 + kk) << 23); \
    A0 *= sc; A1 *= sc; A2 *= sc; \
  }

#define STEP(U) { \
    const float A1p = i2f(__builtin_amdgcn_update_dpp(0, f2i(A1), 0x138, 0xF, 0xF, false)); \
    const float nA0 = c##U * (A0 + A1p); \
    const float nA1 = g##U * fmaf(sk, A1p, A0 + A1); \
    const float nA2 = c##U * (A2 + A1); \
    const bool act = (tbase + (U)) < len; \
    A0 = act ? nA0 : A0; A1 = act ? nA1 : A1; A2 = act ? nA2 : A2; \
  }

  // preamble: producers prefetch window 0 into the A-set
  if (wv != 0) {
    pa0 = PLOAD(0, r0);
    if (has2) pa1 = PLOAD(0, r1);
  }

  for (int w = 0; w < 65; ++w) {
    if (wv != 0) {
      if (w < 64) {
        const bool pre = (w < 63);
        if ((w & 1) == 0) {               // even window: cur=pa, prefetch->pb
          if (pre) { pb0 = PLOAD(w + 1, r0); if (has2) pb1 = PLOAD(w + 1, r1); }
          EMIT(w, r0, pa0)
          if (has2) EMIT(w, r1, pa1)
        } else {                          // odd window: cur=pb, prefetch->pa
          if (pre) { pa0 = PLOAD(w + 1, r0); if (has2) pa1 = PLOAD(w + 1, r1); }
          EMIT(w, r0, pb0)
          if (has2) EMIT(w, r1, pb1)
        }
      }
    } else if (w >= 1) {
      // ---- wave 0: consume window w-1 (written by producers in iter w-1) ----
      const int h = (w - 1) & 1;
      const float* rb = &buf[h][0][0];
      float c0, c1, c2, c3, c4, c5, c6, c7, c8, c9, c10, c11, c12, c13, c14, c15;
      float g0, g1, g2, g3, g4, g5, g6, g7, g8, g9, g10, g11, g12, g13, g14, g15;
#define RD(U) c##U = rb[(U) << 6]; g##U = rb[((U) << 6) + lab];
      RD(0)  RD(1)  RD(2)  RD(3)  RD(4)  RD(5)  RD(6)  RD(7)
      RD(8)  RD(9)  RD(10) RD(11) RD(12) RD(13) RD(14) RD(15)
#undef RD
      // may-alias pin: reads above cannot sink below this store (row 0 is
      // already consumed; the half is dead until producers rewrite it).
      ((volatile float*)rb)[lane] = A0;
      RENORM()
      const int tbase = (w - 1) << 4;
      STEP(0)  STEP(1)  STEP(2)  STEP(3)  STEP(4)  STEP(5)  STEP(6)  STEP(7)
      STEP(8)  STEP(9)  STEP(10) STEP(11) STEP(12) STEP(13) STEP(14) STEP(15)
    }
    barrier_lds();
  }

  // producers publish their LSE partials; one more uniform barrier
  if (wv != 0) {
    float a = ((lane & 15) == 0) ? acc : 0.0f;
    a += __shfl_xor(a, 16);
    a += __shfl_xor(a, 32);
    if (lane == 0) lsePart[wv - 1] = a;
  }
  barrier_lds();

  if (wv == 0) {
    float ae, ae1;
    if (lab_len >= LL) {            // e = 128
      ae  = i2f(__builtin_amdgcn_readlane(f2i(A2), 63));
      ae1 = i2f(__builtin_amdgcn_readlane(f2i(A1), 63));
    } else if (lab_len >= 1) {      // e = 2*lab_len
      ae  = i2f(__builtin_amdgcn_readlane(f2i(A0), lab_len));
      ae1 = i2f(__builtin_amdgcn_readlane(f2i(A1), lab_len - 1));
    } else {
      ae  = i2f(__builtin_amdgcn_readlane(f2i(A0), 0));
      ae1 = ae;
    }
    const float se = ae + ae1;      // linear-space logaddexp
    float loss = (lsePart[0] + lsePart[1] + lsePart[2])
               - LN2 * (__builtin_amdgcn_logf(se) - (float)ctot);
    if (lab_len > len) loss = 0.0f; // feasibility mask
    if (lane == 0) atomicAdd(out, loss * (1.0f / 256.0f));
  }
#undef STEP
#undef RENORM
#undef EMIT
#undef PLOAD
}

extern "C" void kernel_launch(void* const* d_in, const int* in_sizes, int n_in,
                              void* d_out, int out_size, void* d_ws, size_t ws_size,
                              hipStream_t stream) {
  (void)in_sizes; (void)n_in; (void)out_size; (void)d_ws; (void)ws_size;
  hipMemsetAsync(d_out, 0, sizeof(float), stream);   // d_out is poisoned 0xAA
  ctc_fused<<<dim3(BB), dim3(256), 0, stream>>>(
      (const int*)d_in[0], (const float*)d_in[1], (const int*)d_in[2], (float*)d_out);
}